// Round 10
// baseline (151.732 us; speedup 1.0000x reference)
//
#include <hip/hip_runtime.h>
#include <hip/hip_fp16.h>
#include <hip/hip_bf16.h>

// Logic-gate network: 23 layers, widths [128]*16 + [64,32,16,8,4,2,1].
// Node j: out = c0 + c1*a + c2*b + c3*a*b; c = softmax(W[j]) @ GATE_COEFFS.
// N_CELLS = 262144 cells.
//
// R10: node-PAIR processing to halve DS instruction count at constant bytes.
// Layout: 8 fp16 cells/lane, rows = 32 slots x 16B = 512B, 128 rows = 64KB.
// Lanes 0-31 process node j, lanes 32-63 node k (one pair per j-iter):
//   - 2x ds_read_b128 with per-lane row offset (lo half: j's operand row,
//     hi half: k's) deliver a,b for BOTH nodes -> 1 read-inst per node.
//   - 1x full-wave ds_write_b128 stores both results -> 0.5 write/node.
//   DS insts/node: 3 -> 1.5 (bytes unchanged). Disambiguates m134's
//   issue-limit (~6cyc/inst) vs bytes-limit (85B/cyc) hypotheses.
// Coeffs+row offsets come from a 64B PairDesc via per-lane global_load
// (VMEM pipe, L1-resident: ~4KB working set/layer).
// fp16 storage+math (absmax 1.95e-3, thr 9.26e-3). 1024 thr, 2 blocks/CU.

#define N_CELLS     262144
#define TOTAL_NODES 2175
#define TOTAL_PAIRS 1088
#define CELLS       256        // cells per block (32 slots x 8 packed fp16)
#define BLOCK       1024       // 16 waves
#define ROWS        128        // max layer width

__device__ const int LAYER_OFF[24] = {
    0, 128, 256, 384, 512, 640, 768, 896, 1024, 1152, 1280, 1408,
    1536, 1664, 1792, 1920, 2048, 2112, 2144, 2160, 2168, 2172, 2174, 2175
};
// pairs per layer: 64 x16, then 32,16,8,4,2,1,1
__device__ const int PAIR_OFF[24] = {
    0, 64, 128, 192, 256, 320, 384, 448, 512, 576, 640, 704,
    768, 832, 896, 960, 1024, 1056, 1072, 1080, 1084, 1086, 1087, 1088
};

__device__ const float GC[16][4] = {
    {0, 0, 0, 0}, {0, 0, 0, 1}, {0, 1, 0, -1}, {0, 1, 0, 0},
    {0, 0, 1, -1}, {0, 0, 1, 0}, {0, 1, 1, -2}, {0, 1, 1, -1},
    {1, -1, -1, 1}, {1, -1, -1, 2}, {1, 0, -1, 0}, {1, 0, -1, 1},
    {1, -1, 0, 0}, {1, -1, 0, 1}, {1, 0, 0, -1}, {1, 0, 0, 0}
};

// PairDesc: 64B = two 32B half-blocks, one per node of the pair.
// half-block: c0,c1,c2,c3 (half2-dup u32 x4) | ia_off, ib_off, out_off, pad.
// A lane reads ITS node's halves with two dwordx4 loads at p*64 + hi*32 (+16).

__device__ __forceinline__ unsigned int h2u(__half2 h) {
    return *reinterpret_cast<unsigned int*>(&h);
}
__device__ __forceinline__ __half2 u2h2(unsigned int u) {
    return *reinterpret_cast<__half2*>(&u);
}

// ---- Kernel A: build pair descriptors ----
__global__ void coeff_kernel(const float* __restrict__ W,
                             const int* __restrict__ idx_a,
                             const int* __restrict__ idx_b,
                             unsigned int* __restrict__ pdesc) {
    int node = blockIdx.x * blockDim.x + threadIdx.x;
    if (node >= TOTAL_NODES) return;
    const float* w = W + node * 16;
    float v[16];
    float m = -1e30f;
    #pragma unroll
    for (int i = 0; i < 16; ++i) { v[i] = w[i]; m = fmaxf(m, v[i]); }
    float s = 0.f;
    #pragma unroll
    for (int i = 0; i < 16; ++i) { v[i] = expf(v[i] - m); s += v[i]; }
    float inv = 1.0f / s;
    float c0 = 0.f, c1 = 0.f, c2 = 0.f, c3 = 0.f;
    #pragma unroll
    for (int i = 0; i < 16; ++i) {
        float p = v[i] * inv;
        c0 += p * GC[i][0];
        c1 += p * GC[i][1];
        c2 += p * GC[i][2];
        c3 += p * GC[i][3];
    }
    // locate layer
    int li = 0;
    #pragma unroll
    for (int l = 0; l < 23; ++l) if (node >= LAYER_OFF[l + 1]) li = l + 1;
    int nu = node - LAYER_OFF[li];
    int p  = PAIR_OFF[li] + (nu >> 1);
    int h  = nu & 1;

    unsigned int cc0 = h2u(__half2half2(__float2half(c0)));
    unsigned int cc1 = h2u(__half2half2(__float2half(c1)));
    unsigned int cc2 = h2u(__half2half2(__float2half(c2)));
    unsigned int cc3 = h2u(__half2half2(__float2half(c3)));
    unsigned int iao = (unsigned int)idx_a[node] * 512u;
    unsigned int ibo = (unsigned int)idx_b[node] * 512u;
    unsigned int oo  = (unsigned int)nu * 512u;

    int reps = (li == 22) ? 2 : 1;     // width-1 layer: duplicate into both halves
    for (int r = 0; r < reps; ++r) {
        unsigned int* d = pdesc + p * 16 + (h + r) * 8;
        d[0] = cc0; d[1] = cc1; d[2] = cc2; d[3] = cc3;
        d[4] = iao; d[5] = ibo; d[6] = oo;  d[7] = 0;
    }
}

// One layer phase: wave q handles pairs [q*PP, q*PP+PP) of this layer.
// Lane<32 computes node0 of the pair, lane>=32 node1.
template<int PP>
__device__ __forceinline__ void layer_step(const unsigned int* __restrict__ pdesc,
                                           int poff, int npairs,
                                           char* __restrict__ lds,
                                           int q, int hi32, int slot16) {
    const int p0 = q * PP;
    uint4 res[PP];
    unsigned int oo[PP];
    const bool active = (p0 < npairs);

    if (active) {
        #pragma unroll
        for (int m = 0; m < PP; ++m) {
            int pu = __builtin_amdgcn_readfirstlane(p0 + m) + poff;
            const unsigned int* pd = pdesc + pu * 16 + hi32;   // per-lane half
            uint4 cf = *reinterpret_cast<const uint4*>(pd);     // c0..c3
            uint4 mo = *reinterpret_cast<const uint4*>(pd + 4); // ia,ib,out,pad
            uint4 av = *reinterpret_cast<const uint4*>(lds + mo.x + slot16);
            uint4 bv = *reinterpret_cast<const uint4*>(lds + mo.y + slot16);
            __half2 C0 = u2h2(cf.x), C1 = u2h2(cf.y), C2 = u2h2(cf.z), C3 = u2h2(cf.w);
            __half2 a0 = u2h2(av.x), a1 = u2h2(av.y), a2 = u2h2(av.z), a3 = u2h2(av.w);
            __half2 b0 = u2h2(bv.x), b1 = u2h2(bv.y), b2 = u2h2(bv.z), b3 = u2h2(bv.w);
            // out = a*(c1 + c3*b) + (c0 + c2*b)
            res[m].x = h2u(__hfma2(a0, __hfma2(C3, b0, C1), __hfma2(C2, b0, C0)));
            res[m].y = h2u(__hfma2(a1, __hfma2(C3, b1, C1), __hfma2(C2, b1, C0)));
            res[m].z = h2u(__hfma2(a2, __hfma2(C3, b2, C1), __hfma2(C2, b2, C0)));
            res[m].w = h2u(__hfma2(a3, __hfma2(C3, b3, C1), __hfma2(C2, b3, C0)));
            oo[m] = mo.z;
        }
    }
    __syncthreads();                   // all reads done
    if (active) {
        #pragma unroll
        for (int m = 0; m < PP; ++m) {
            *reinterpret_cast<uint4*>(lds + oo[m] + slot16) = res[m];  // b128 write
        }
    }
    __syncthreads();                   // all writes done
}

// ---- Kernel B: the network. 256 cells/block; 64KB LDS, rows of 32x16B. ----
__global__ __launch_bounds__(BLOCK, 4)
void net_kernel(const float* __restrict__ x,
                const unsigned int* __restrict__ pdesc,
                float* __restrict__ out) {
    __shared__ uint4 buf[ROWS][32];    // 128 rows x 512B = 64KB -> 2 blocks/CU

    const int t      = threadIdx.x;
    const int lane   = t & 63;
    const int q      = t >> 6;                 // wave id 0..15
    const int hi32   = (lane >> 5) * 8;        // dword offset of my pair-half
    const int slot16 = (lane & 31) * 16;       // byte offset within row
    char* lds = reinterpret_cast<char*>(&buf[0][0]);
    const size_t base = (size_t)blockIdx.x * CELLS;

    // Stage x (256 cells x 16 f32 = 16KB) -> fp16 rows: row k, slot c>>3, sub c&7.
    {
        const float4* xv = reinterpret_cast<const float4*>(x + base * 16);
        __half* hp = reinterpret_cast<__half*>(lds);
        float4 v = xv[t];                 // coalesced: 1024 float4
        int c  = t >> 2;                  // cell 0..255
        int k  = (t & 3) << 2;            // feature base
        int idx = (c >> 3) * 8 + (c & 7); // slot*8 + sub
        hp[(k + 0) * 256 + idx] = __float2half(v.x);
        hp[(k + 1) * 256 + idx] = __float2half(v.y);
        hp[(k + 2) * 256 + idx] = __float2half(v.z);
        hp[(k + 3) * 256 + idx] = __float2half(v.w);
    }
    __syncthreads();

    // Main layers 0..15: 64 pairs each, PP=4.
    #pragma unroll 1
    for (int li = 0; li < 16; ++li)
        layer_step<4>(pdesc, li * 64, 64, lds, q, hi32, slot16);
    // Tail: pairs 32,16,8,4,2,1,1.
    layer_step<2>(pdesc, 1024, 32, lds, q, hi32, slot16);
    layer_step<1>(pdesc, 1056, 16, lds, q, hi32, slot16);
    layer_step<1>(pdesc, 1072,  8, lds, q, hi32, slot16);
    layer_step<1>(pdesc, 1080,  4, lds, q, hi32, slot16);
    layer_step<1>(pdesc, 1084,  2, lds, q, hi32, slot16);
    layer_step<1>(pdesc, 1086,  1, lds, q, hi32, slot16);
    layer_step<1>(pdesc, 1087,  1, lds, q, hi32, slot16);

    // Final value lives in row 0 (all 256 cells).
    if (t < CELLS) {
        const __half* hp = reinterpret_cast<const __half*>(lds);
        out[base + t] = __half2float(hp[t]);   // row0: slot*8+sub == cell index
    }
}

extern "C" void kernel_launch(void* const* d_in, const int* in_sizes, int n_in,
                              void* d_out, int out_size, void* d_ws, size_t ws_size,
                              hipStream_t stream) {
    const float* x  = (const float*)d_in[0];
    const float* W  = (const float*)d_in[1];
    const int*   ia = (const int*)d_in[2];
    const int*   ib = (const int*)d_in[3];
    unsigned int* pdesc = (unsigned int*)d_ws;   // 1088 * 64B = 69.6 KB scratch

    coeff_kernel<<<(TOTAL_NODES + 255) / 256, 256, 0, stream>>>(W, ia, ib, pdesc);

    const int grid = N_CELLS / CELLS;    // 1024 blocks
    net_kernel<<<grid, BLOCK, 0, stream>>>(x, pdesc, (float*)d_out);
}

// Round 12
// 137.141 us; speedup vs baseline: 1.1064x; 1.1064x over previous
//
#include <hip/hip_runtime.h>
#include <hip/hip_fp16.h>
#include <hip/hip_bf16.h>

// Logic-gate network: 23 layers, widths [128]*16 + [64,32,16,8,4,2,1].
// Node j: out = c0 + c1*a + c2*b + c3*a*b; c = softmax(W[j]) @ GATE_COEFFS.
// N_CELLS = 262144 cells.
//
// R12: 2-LAYER FUSION on the R9 structure (R11 lesson: cooperative launch
// does not survive graph capture -> back to two dispatches).
// A fused unit computes one layer-(L+1) node by recomputing its two layer-L
// inputs from layer-(L-1) rows: 4 ds_read_b64 + 1 ds_write_b64 per 2 layers
// (vs 6 DS insts unfused) -> DS bytes x0.833 (the binding resource: R9 ran
// at 74.7 B/cyc of the ~85 B/cyc LDS ceiling), barriers halved (24 vs 47),
// redundant +6 pk-fma/unit lands on the half-idle VALU (48%).
// Fused 64B descriptors on the wave-uniform SCALAR path (R10 lesson).
// Pairs: (0,1)..(14,15), (16,17), (18,19), (20,21); layer 22 via identity-
// coefficient pseudo-fusion (cA=cB=[0,1,0,0]) so one code path serves all.
// fp16 storage+math (R9 absmax 1.95e-3, thr 9.26e-3). 1024 thr, 2 blk/CU.

#define N_CELLS     262144
#define TOTAL_NODES 2175
#define TOTAL_FUSED 1067       // 8*128 main + 32 + 8 + 2 + 1
#define CELLS       256        // cells per block (64 lanes x 4 packed fp16)
#define BLOCK       1024       // 16 waves
#define ROWS        128        // max layer width

__device__ const int LAYER_OFF[24] = {
    0, 128, 256, 384, 512, 640, 768, 896, 1024, 1152, 1280, 1408,
    1536, 1664, 1792, 1920, 2048, 2112, 2144, 2160, 2168, 2172, 2174, 2175
};

__device__ const float GC[16][4] = {
    {0, 0, 0, 0}, {0, 0, 0, 1}, {0, 1, 0, -1}, {0, 1, 0, 0},
    {0, 0, 1, -1}, {0, 0, 1, 0}, {0, 1, 1, -2}, {0, 1, 1, -1},
    {1, -1, -1, 1}, {1, -1, -1, 2}, {1, 0, -1, 0}, {1, 0, -1, 1},
    {1, -1, 0, 0}, {1, -1, 0, 1}, {1, 0, 0, -1}, {1, 0, 0, 0}
};

__device__ __forceinline__ unsigned int h2u(__half2 h) {
    return *reinterpret_cast<unsigned int*>(&h);
}
__device__ __forceinline__ __half2 u2h2(unsigned int u) {
    return *reinterpret_cast<__half2*>(&u);
}

// softmax(W[node]) @ GC -> 4 floats
__device__ __forceinline__ void softgc(const float* __restrict__ w, float* c) {
    float v[16];
    float m = -1e30f;
    #pragma unroll
    for (int i = 0; i < 16; ++i) { v[i] = w[i]; m = fmaxf(m, v[i]); }
    float s = 0.f;
    #pragma unroll
    for (int i = 0; i < 16; ++i) { v[i] = expf(v[i] - m); s += v[i]; }
    float inv = 1.0f / s;
    c[0] = c[1] = c[2] = c[3] = 0.f;
    #pragma unroll
    for (int i = 0; i < 16; ++i) {
        float p = v[i] * inv;
        c[0] += p * GC[i][0];
        c[1] += p * GC[i][1];
        c[2] += p * GC[i][2];
        c[3] += p * GC[i][3];
    }
}

__device__ __forceinline__ uint4 packc(const float* c) {
    uint4 r;
    r.x = h2u(__half2half2(__float2half(c[0])));
    r.y = h2u(__half2half2(__float2half(c[1])));
    r.z = h2u(__half2half2(__float2half(c[2])));
    r.w = h2u(__half2half2(__float2half(c[3])));
    return r;
}

// ---- Kernel A: build fused descriptors (64B each):
//   [0]=cA, [1]=cB, [2]=cO (half2-dup x4), [3]={iaA, ibA, iaB, ibB} rows.
__global__ void coeff_kernel(const float* __restrict__ W,
                             const int* __restrict__ idx_a,
                             const int* __restrict__ idx_b,
                             uint4* __restrict__ fdesc) {
    int f = blockIdx.x * blockDim.x + threadIdx.x;
    if (f >= TOTAL_FUSED) return;

    int L1, n;
    bool ident = false;
    if (f < 1024)      { int p = f >> 7; L1 = 2 * p + 1; n = f & 127; }
    else if (f < 1056) { L1 = 17; n = f - 1024; }
    else if (f < 1064) { L1 = 19; n = f - 1056; }
    else if (f < 1066) { L1 = 21; n = f - 1064; }
    else               { L1 = 22; n = 0; ident = true; }

    int g1 = LAYER_OFF[L1] + n;
    float cO[4], cA[4], cB[4];
    softgc(W + 16 * g1, cO);
    uint4 idx;
    if (!ident) {
        int L0 = L1 - 1;
        int gA = LAYER_OFF[L0] + idx_a[g1];
        int gB = LAYER_OFF[L0] + idx_b[g1];
        softgc(W + 16 * gA, cA);
        softgc(W + 16 * gB, cB);
        idx.x = idx_a[gA]; idx.y = idx_b[gA];
        idx.z = idx_a[gB]; idx.w = idx_b[gB];
    } else {
        // layer 22 solo: A = rowA, B = rowB via identity gates, out = gate(A,B)
        cA[0] = 0.f; cA[1] = 1.f; cA[2] = 0.f; cA[3] = 0.f;
        cB[0] = 0.f; cB[1] = 1.f; cB[2] = 0.f; cB[3] = 0.f;
        idx.x = idx.y = idx_a[g1];
        idx.z = idx.w = idx_b[g1];
    }
    fdesc[f * 4 + 0] = packc(cA);
    fdesc[f * 4 + 1] = packc(cB);
    fdesc[f * 4 + 2] = packc(cO);
    fdesc[f * 4 + 3] = idx;
}

// gate(a,b) = a*(c1 + c3*b) + (c0 + c2*b), packed fp16
__device__ __forceinline__ __half2 gate2(__half2 a, __half2 b, uint4 c) {
    return __hfma2(a, __hfma2(u2h2(c.w), b, u2h2(c.y)),
                      __hfma2(u2h2(c.z), b, u2h2(c.x)));
}

// One FUSED step (2 layers): wave q computes fused units [q*PER, q*PER+PER).
// Phase 1: 4 gathers from layer-(L-1) rows, recompute A,B, compute O. Barrier.
// Phase 2: write O to out-row nu. Barrier.
template<int PER>
__device__ __forceinline__ void fused_step(const uint4* __restrict__ fdesc,
                                           int off, int w,
                                           uint2 (* __restrict__ buf)[64],
                                           int q, int lane) {
    const int n0 = q * PER;
    uint2 res[PER];
    const bool active = (n0 < w);

    if (active) {
        #pragma unroll
        for (int j = 0; j < PER; ++j) {
            int nu = __builtin_amdgcn_readfirstlane(n0 + j);
            const uint4* fd = fdesc + 4 * (off + nu);   // scalar s_load x16
            uint4 cAc = fd[0], cBc = fd[1], cOc = fd[2], idx = fd[3];
            uint2 vaA = buf[idx.x][lane];               // 4x ds_read_b64
            uint2 vbA = buf[idx.y][lane];
            uint2 vaB = buf[idx.z][lane];
            uint2 vbB = buf[idx.w][lane];
            __half2 A0 = gate2(u2h2(vaA.x), u2h2(vbA.x), cAc);
            __half2 A1 = gate2(u2h2(vaA.y), u2h2(vbA.y), cAc);
            __half2 B0 = gate2(u2h2(vaB.x), u2h2(vbB.x), cBc);
            __half2 B1 = gate2(u2h2(vaB.y), u2h2(vbB.y), cBc);
            __half2 O0 = gate2(A0, B0, cOc);
            __half2 O1 = gate2(A1, B1, cOc);
            res[j].x = h2u(O0);
            res[j].y = h2u(O1);
        }
    }
    __syncthreads();                              // all reads done
    if (active) {
        #pragma unroll
        for (int j = 0; j < PER; ++j) {
            int nu = __builtin_amdgcn_readfirstlane(n0 + j);
            buf[nu][lane] = res[j];               // ds_write_b64
        }
    }
    __syncthreads();                              // all writes done
}

// ---- Kernel B: the network. 256 cells/block; single 64KB LDS buffer. ----
__global__ __launch_bounds__(BLOCK, 4)
void net_kernel(const float* __restrict__ x,
                const uint4* __restrict__ fdesc,
                float* __restrict__ out) {
    // 128 rows * 64 lanes * 8B = 64 KB -> 2 blocks/CU (32 waves/CU).
    __shared__ uint2 buf[ROWS][64];

    const int t    = threadIdx.x;
    const int lane = t & 63;        // cells lane, lane+64, lane+128, lane+192
    const int q    = t >> 6;        // wave id 0..15
    const size_t base = (size_t)blockIdx.x * CELLS;

    // Stage x (256 cells x 16 f32 = 16 KB) -> packed fp16 buf[k][lane][4].
    {
        const float4* xv = reinterpret_cast<const float4*>(x + base * 16);
        __half* hp = reinterpret_cast<__half*>(&buf[0][0]);
        float4 v = xv[t];                 // coalesced: 1024 float4
        int c  = t >> 2;                  // cell 0..255
        int k  = (t & 3) << 2;            // feature base
        int h  = c >> 6;                  // sub-slot 0..3
        int cl = c & 63;
        hp[((k + 0) * 64 + cl) * 4 + h] = __float2half(v.x);
        hp[((k + 1) * 64 + cl) * 4 + h] = __float2half(v.y);
        hp[((k + 2) * 64 + cl) * 4 + h] = __float2half(v.z);
        hp[((k + 3) * 64 + cl) * 4 + h] = __float2half(v.w);
    }
    __syncthreads();

    // Main fused pairs (0,1)..(14,15): 128 units each, PER=8 (16 waves).
    #pragma unroll 1
    for (int p = 0; p < 8; ++p)
        fused_step<8>(fdesc, p * 128, 128, buf, q, lane);
    // Tail fused pairs: (16,17)=32 units, (18,19)=8, (20,21)=2, layer22=1.
    fused_step<2>(fdesc, 1024, 32, buf, q, lane);
    fused_step<1>(fdesc, 1056,  8, buf, q, lane);
    fused_step<1>(fdesc, 1064,  2, buf, q, lane);
    fused_step<1>(fdesc, 1066,  1, buf, q, lane);

    // Final layer width 1: row 0, 4 packed cells per lane.
    if (t < CELLS) {
        int cl = t & 63, h = t >> 6;
        uint2 p = buf[0][cl];                 // broadcast read
        unsigned int u = (h < 2) ? p.x : p.y;
        __half2 hh = u2h2(u);
        out[base + t] = (h & 1) ? __high2float(hh) : __low2float(hh);
    }
}

extern "C" void kernel_launch(void* const* d_in, const int* in_sizes, int n_in,
                              void* d_out, int out_size, void* d_ws, size_t ws_size,
                              hipStream_t stream) {
    const float* x  = (const float*)d_in[0];
    const float* W  = (const float*)d_in[1];
    const int*   ia = (const int*)d_in[2];
    const int*   ib = (const int*)d_in[3];
    uint4* fdesc    = (uint4*)d_ws;   // 1067 * 64 B = 68.3 KB scratch

    coeff_kernel<<<(TOTAL_FUSED + 255) / 256, 256, 0, stream>>>(W, ia, ib, fdesc);

    const int grid = N_CELLS / CELLS;    // 1024 blocks
    net_kernel<<<grid, BLOCK, 0, stream>>>(x, fdesc, (float*)d_out);
}